// Round 8
// baseline (282.447 us; speedup 1.0000x reference)
//
#include <hip/hip_runtime.h>
#include <hip/hip_bf16.h>

// GraphConv (PyG, aggr='add') + ReLU on MI355X — fp32 in/out, bf16 internals.
//   out = relu( segment_sum(x[src] -> dst) @ W_rel^T + b_rel + x @ W_root^T )
// N=50000, E=800000, D=128.
//
// Round 8: reorder was 57 µs latency-bound (1 returning atomic/thread,
// VALUBusy 0.5%; WRITE_SIZE 53 MB = 16x line-churn amplification on 4 B
// scatters). Now 4 edges/thread -> 4 concurrent atomicAdd returns +
// nontemporal scatter stores. hist batched 4-wide too. Gather is fused into
// the MFMA GEMM (agg rows staged in LDS, stride 136 -> 2-way = free), killing
// the 25.6 MB aggb round trip and one launch (6 -> 5).

#define N_NODES 50000
#define N_EDGES 800000
#define D 128
#define NPB 32      // nodes per fp32-gemm block (mid tier)
#define KC 32       // k per chunk (mid tier)
#define SROW 136    // LDS agg-row stride (ushorts); 136*2=272 B, 2-way banks

#define CVT_N  (N_NODES * (D / 2))   // 3,200,000 ushort2 conversions
#define PACK_N (8 * 8 * 64 * 8)      // 32,768 packed B-fragment elements

typedef __attribute__((ext_vector_type(8))) short short8;   // 8 bf16 = 4 VGPRs
typedef __attribute__((ext_vector_type(4))) float floatx4;

__device__ __forceinline__ float bf2f(unsigned short u) {
    return __uint_as_float((unsigned int)u << 16);
}
__device__ __forceinline__ unsigned short f2bf(float f) {
    __hip_bfloat16 h = __float2bfloat16(f);
    return *(unsigned short*)&h;
}

// int64 node-id array => every odd int32 word is 0 (ids < 50000).
// Must run with all 64 lanes active (call before any early return).
__device__ __forceinline__ int wave_detect_i64(const int* __restrict__ ei) {
    int lane = threadIdx.x & 63;
    int v = ei[2 * lane + 1];
    return __ballot(v == 0) == ~0ull;
}

// ---------------- utility ----------------
__global__ __launch_bounds__(256) void zero_f4_kernel(float4* __restrict__ p, int n4) {
    int i = blockIdx.x * 256 + threadIdx.x;
    if (i < n4) p[i] = make_float4(0.f, 0.f, 0.f, 0.f);
}

// flag-based detect kept only for the low-tier scatter fallback
__global__ void detect_kernel(const int* __restrict__ ei, int* __restrict__ flag) {
    if (threadIdx.x == 0 && blockIdx.x == 0) {
        int any = 0;
        for (int i = 0; i < 64; ++i) any |= ei[2 * i + 1];
        flag[0] = (any == 0) ? 1 : 0;
    }
}

// ---------------- fused prep: cvt_x + pack_frag + zero deg ----------------
__global__ __launch_bounds__(256) void prep_kernel(const float2* __restrict__ x2,
                                                   ushort2* __restrict__ xb2,
                                                   const float* __restrict__ Wrel,
                                                   const float* __restrict__ Wroot,
                                                   unsigned short* __restrict__ pwc,
                                                   int* __restrict__ deg) {
    int i = blockIdx.x * 256 + threadIdx.x;
    if (i < CVT_N) {
        float2 f = x2[i];
        xb2[i] = make_ushort2(f2bf(f.x), f2bf(f.y));
    } else if (i < CVT_N + PACK_N) {
        // pwc[((t*8+n0)*64+lane)*8+j] = W_cat[n0*16+(lane&15)][t*32+(lane>>4)*8+j]
        int idx  = i - CVT_N;
        int j    = idx & 7;
        int lane = (idx >> 3) & 63;
        int n0   = (idx >> 9) & 7;
        int t    = idx >> 12;
        int n = n0 * 16 + (lane & 15);
        int k = t * 32 + (lane >> 4) * 8 + j;
        float w = (k < D) ? Wrel[n * D + k] : Wroot[n * D + (k - D)];
        pwc[idx] = f2bf(w);
    } else if (i < CVT_N + PACK_N + N_NODES) {
        deg[i - CVT_N - PACK_N] = 0;
    }
}

// ---------------- CSR build (4 edges/thread for atomic MLP) ----------------
__global__ __launch_bounds__(256) void hist_kernel(const int* __restrict__ ei,
                                                   int* __restrict__ deg) {
    int i64 = wave_detect_i64(ei);
    int base = (blockIdx.x * 256 + threadIdx.x) * 4;
    if (base >= N_EDGES) return;
    int d0, d1, d2, d3;
    if (i64) {
        int4 a = *(const int4*)&ei[2 * N_EDGES + 2 * base];
        int4 b = *(const int4*)&ei[2 * N_EDGES + 2 * base + 4];
        d0 = a.x; d1 = a.z; d2 = b.x; d3 = b.z;
    } else {
        int4 v = *(const int4*)&ei[N_EDGES + base];
        d0 = v.x; d1 = v.y; d2 = v.z; d3 = v.w;
    }
    if ((unsigned)d0 < N_NODES) atomicAdd(&deg[d0], 1);
    if ((unsigned)d1 < N_NODES) atomicAdd(&deg[d1], 1);
    if ((unsigned)d2 < N_NODES) atomicAdd(&deg[d2], 1);
    if ((unsigned)d3 < N_NODES) atomicAdd(&deg[d3], 1);
}

__device__ __forceinline__ int wave_iscan(int v, int lane) {
#pragma unroll
    for (int off = 1; off < 64; off <<= 1) {
        int u = __shfl_up(v, off, 64);
        if (lane >= off) v += u;
    }
    return v;
}

// Single-block scan. offsets[0]=0, offsets[i+1]=incl sum; cursor[i]=excl sum.
__global__ __launch_bounds__(1024) void scan_kernel(const int* __restrict__ deg,
                                                    int* __restrict__ offsets,
                                                    int* __restrict__ cursor) {
    __shared__ int wsum[16];
    __shared__ int base_s;
    int t = threadIdx.x, lane = t & 63, w = t >> 6;
    if (t == 0) { base_s = 0; offsets[0] = 0; }
    __syncthreads();
    for (int c0 = 0; c0 < N_NODES; c0 += 1024) {
        int idx = c0 + t;
        int v = (idx < N_NODES) ? deg[idx] : 0;
        int inc = wave_iscan(v, lane);
        if (lane == 63) wsum[w] = inc;
        __syncthreads();
        if (w == 0) {
            int s = (lane < 16) ? wsum[lane] : 0;
            int si = wave_iscan(s, lane);
            if (lane < 16) wsum[lane] = si - s;   // exclusive wave base
        }
        __syncthreads();
        int tot = base_s + wsum[w] + inc;
        if (idx < N_NODES) {
            offsets[idx + 1] = tot;
            cursor[idx] = tot - v;                // exclusive prefix
        }
        __syncthreads();
        if (t == 1023) base_s = tot;
        __syncthreads();
    }
}

// 4 edges/thread: 4 independent returning atomics in flight, NT scatter stores.
__global__ __launch_bounds__(256) void reorder_kernel(const int* __restrict__ ei,
                                                      int* __restrict__ cursor,
                                                      int* __restrict__ csr_src) {
    int i64 = wave_detect_i64(ei);
    int base = (blockIdx.x * 256 + threadIdx.x) * 4;
    if (base >= N_EDGES) return;
    int s0, s1, s2, s3, d0, d1, d2, d3;
    if (i64) {
        int4 a = *(const int4*)&ei[2 * base];
        int4 b = *(const int4*)&ei[2 * base + 4];
        s0 = a.x; s1 = a.z; s2 = b.x; s3 = b.z;
        int4 c = *(const int4*)&ei[2 * N_EDGES + 2 * base];
        int4 e = *(const int4*)&ei[2 * N_EDGES + 2 * base + 4];
        d0 = c.x; d1 = c.z; d2 = e.x; d3 = e.z;
    } else {
        int4 sv = *(const int4*)&ei[base];
        int4 dv = *(const int4*)&ei[N_EDGES + base];
        s0 = sv.x; s1 = sv.y; s2 = sv.z; s3 = sv.w;
        d0 = dv.x; d1 = dv.y; d2 = dv.z; d3 = dv.w;
    }
    bool v0 = (unsigned)s0 < N_NODES && (unsigned)d0 < N_NODES;
    bool v1 = (unsigned)s1 < N_NODES && (unsigned)d1 < N_NODES;
    bool v2 = (unsigned)s2 < N_NODES && (unsigned)d2 < N_NODES;
    bool v3 = (unsigned)s3 < N_NODES && (unsigned)d3 < N_NODES;
    int p0 = v0 ? atomicAdd(&cursor[d0], 1) : 0;   // 4 independent round-trips
    int p1 = v1 ? atomicAdd(&cursor[d1], 1) : 0;
    int p2 = v2 ? atomicAdd(&cursor[d2], 1) : 0;
    int p3 = v3 ? atomicAdd(&cursor[d3], 1) : 0;
    if (v0) __builtin_nontemporal_store(s0, &csr_src[p0]);
    if (v1) __builtin_nontemporal_store(s1, &csr_src[p1]);
    if (v2) __builtin_nontemporal_store(s2, &csr_src[p2]);
    if (v3) __builtin_nontemporal_store(s3, &csr_src[p3]);
}

// ---------------- fused gather + MFMA GEMM + bias + ReLU ----------------
// Block = 4 waves = 64 nodes. Phase 1: wave w gathers rows for its 16 nodes
// (4-wide pipelined row loads) into LDS (stride 136 -> conflict-free-ish).
// Phase 2: 1 wave = 16 nodes x 128 outs, 8 k-steps of 32; A from LDS (agg)
// and global (x); B pre-packed fragments; acc in 32 VGPRs.
// Layouts (verified): A[m=lane&15][k=quad*8+j], D: col=lane&15, row=quad*4+reg.
__global__ __launch_bounds__(256) void GraphConvLayer_55783035240593_kernel(
        const ushort2* __restrict__ xb2,
        const unsigned short* __restrict__ xb,
        const int* __restrict__ csr_src,
        const int* __restrict__ offsets,
        const unsigned short* __restrict__ pwc,
        const float* __restrict__ b_rel,
        float* __restrict__ out) {
    __shared__ unsigned short sA[64 * SROW];   // 17408 B
    int wid  = threadIdx.x >> 6;
    int lane = threadIdx.x & 63;
    int wbase = blockIdx.x * 64 + wid * 16;    // first node of this wave

    // ---- gather phase ----
    for (int li = 0; li < 16; ++li) {
        int node = wbase + li;
        float ax = 0.f, ay = 0.f;
        if (node < N_NODES) {
            int beg = offsets[node], end = offsets[node + 1];
            for (int e = beg; e < end; e += 64) {
                int cnt = end - e;
                if (cnt > 64) cnt = 64;
                int myidx = (lane < cnt) ? csr_src[e + lane] : 0;
                for (int j = 0; j < cnt; j += 4) {
                    int s0 = __shfl(myidx, j);
                    int s1 = __shfl(myidx, j + 1);   // lanes >= cnt hold 0 (valid row)
                    int s2 = __shfl(myidx, j + 2);
                    int s3 = __shfl(myidx, j + 3);
                    ushort2 u0 = xb2[(size_t)s0 * (D / 2) + lane];
                    ushort2 u1 = xb2[(size_t)s1 * (D / 2) + lane];
                    ushort2 u2 = xb2[(size_t)s2 * (D / 2) + lane];
                    ushort2 u3 = xb2[(size_t)s3 * (D / 2) + lane];
                    float m1 = (j + 1 < cnt) ? 1.f : 0.f;
                    float m2 = (j + 2 < cnt) ? 1.f : 0.f;
                    float m3 = (j + 3 < cnt) ? 1.f : 0.f;
                    ax += bf2f(u0.x) + m1 * bf2f(u1.x) + m2 * bf2f(u2.x) + m3 * bf2f(u3.x);
                    ay += bf2f(u0.y) + m1 * bf2f(u1.y) + m2 * bf2f(u2.y) + m3 * bf2f(u3.y);
                }
            }
        }
        *(ushort2*)&sA[(wid * 16 + li) * SROW + 2 * lane] =
            make_ushort2(f2bf(ax), f2bf(ay));
    }
    __syncthreads();

    // ---- MFMA phase ----
    if (wbase >= N_NODES) return;              // whole-wave uniform (N%16==0)
    int m = lane & 15, quad = lane >> 4;
    const unsigned short* arow = &sA[(wid * 16 + m) * SROW + quad * 8];
    const unsigned short* xrow = xb + (size_t)(wbase + m) * D + quad * 8;

    floatx4 acc[8];
#pragma unroll
    for (int n0 = 0; n0 < 8; ++n0) acc[n0] = (floatx4){0.f, 0.f, 0.f, 0.f};

#pragma unroll
    for (int t = 0; t < 8; ++t) {
        short8 afrag = (t < 4) ? *(const short8*)(arow + t * 32)
                               : *(const short8*)(xrow + (t - 4) * 32);
        const unsigned short* bbase = pwc + ((size_t)t * 8 * 64 + lane) * 8;
#pragma unroll
        for (int n0 = 0; n0 < 8; ++n0) {
            short8 bfrag = *(const short8*)(bbase + (size_t)n0 * 64 * 8);
            acc[n0] = __builtin_amdgcn_mfma_f32_16x16x32_bf16(afrag, bfrag, acc[n0], 0, 0, 0);
        }
    }

#pragma unroll
    for (int n0 = 0; n0 < 8; ++n0) {
        int n = n0 * 16 + m;
        float bias = b_rel[n];
#pragma unroll
        for (int r = 0; r < 4; ++r) {
            int node = wbase + quad * 4 + r;
            out[(size_t)node * D + n] = fmaxf(acc[n0][r] + bias, 0.f);
        }
    }
}

// ---------------- mid tier: fp32 CSR + VALU GEMM ----------------
__global__ __launch_bounds__(256) void pack_w_kernel(const float* __restrict__ W,
                                                     float* __restrict__ pw) {
    int idx = blockIdx.x * 256 + threadIdx.x;
    if (idx >= D * D) return;
    int o = idx >> 7, k = idx & 127;
    pw[k * D + o] = W[o * D + k];
}

__global__ __launch_bounds__(256) void gather_kernel(const float2* __restrict__ x2,
                                                     const int* __restrict__ csr_src,
                                                     const int* __restrict__ offsets,
                                                     float2* __restrict__ agg2) {
    int node = blockIdx.x * 4 + (threadIdx.x >> 6);
    int lane = threadIdx.x & 63;
    if (node >= N_NODES) return;
    int beg = offsets[node], end = offsets[node + 1];
    float2 acc = make_float2(0.f, 0.f);
    for (int e = beg; e < end; ++e) {
        int s = csr_src[e];
        float2 f = x2[(size_t)s * (D / 2) + lane];
        acc.x += f.x;
        acc.y += f.y;
    }
    agg2[(size_t)node * (D / 2) + lane] = acc;
}

__global__ __launch_bounds__(256) void scatter_kernel(const float2* __restrict__ x2,
                                                      const int* __restrict__ ei,
                                                      const int* __restrict__ flag,
                                                      float* __restrict__ agg) {
    int wave = threadIdx.x >> 6;
    int lane = threadIdx.x & 63;
    int e = blockIdx.x * 4 + wave;
    if (e >= N_EDGES) return;
    int i64 = flag ? flag[0] : 0;
    int s, d;
    if (i64) { s = ei[2 * e]; d = ei[2 * N_EDGES + 2 * e]; }
    else     { s = ei[e];     d = ei[N_EDGES + e]; }
    if ((unsigned)s >= N_NODES || (unsigned)d >= N_NODES) return;
    float2 f = x2[(size_t)s * (D / 2) + lane];
    atomicAdd(&agg[(size_t)d * D + 2 * lane + 0], f.x);
    atomicAdd(&agg[(size_t)d * D + 2 * lane + 1], f.y);
}

__global__ __launch_bounds__(256) void gemm_f32_kernel(
        const float2* __restrict__ x2,
        const float* __restrict__ pwrel,
        const float* __restrict__ pwroot,
        const float* __restrict__ b_rel,
        float* __restrict__ out) {
    __shared__ float sWrel[KC * D];
    __shared__ float sWroot[KC * D];
    __shared__ float2 sAm[NPB * (KC / 2)];
    __shared__ float2 sXm[NPB * (KC / 2)];

    int t = threadIdx.x;
    int node0 = blockIdx.x * NPB;
    int tn = t >> 5;
    int to = t & 31;

    float acc[4][4];
#pragma unroll
    for (int a = 0; a < 4; ++a)
#pragma unroll
        for (int b = 0; b < 4; ++b) acc[a][b] = 0.0f;

    for (int c = 0; c < 4; ++c) {
        __syncthreads();
#pragma unroll
        for (int r = 0; r < 4; ++r) {
            int i = r * 256 + t;
            ((float4*)sWrel)[i]  = ((const float4*)(pwrel  + c * KC * D))[i];
            ((float4*)sWroot)[i] = ((const float4*)(pwroot + c * KC * D))[i];
        }
#pragma unroll
        for (int r = 0; r < 2; ++r) {
            int i = r * 256 + t;
            int n = i >> 4, k2 = i & 15;
            int node = node0 + n;
            float2 av = make_float2(0.f, 0.f), xv = make_float2(0.f, 0.f);
            if (node < N_NODES) {
                av = ((const float2*)out)[(size_t)node * (D / 2) + c * (KC / 2) + k2];
                xv = x2[(size_t)node * (D / 2) + c * (KC / 2) + k2];
            }
            sAm[i] = av;
            sXm[i] = xv;
        }
        __syncthreads();

#pragma unroll
        for (int k2 = 0; k2 < KC / 2; ++k2) {
            float4 wr0 = *(const float4*)&sWrel[(2 * k2 + 0) * D + to * 4];
            float4 wr1 = *(const float4*)&sWrel[(2 * k2 + 1) * D + to * 4];
            float4 wt0 = *(const float4*)&sWroot[(2 * k2 + 0) * D + to * 4];
            float4 wt1 = *(const float4*)&sWroot[(2 * k2 + 1) * D + to * 4];
#pragma unroll
            for (int ni = 0; ni < 4; ++ni) {
                float2 a  = sAm[(tn * 4 + ni) * (KC / 2) + k2];
                float2 xx = sXm[(tn * 4 + ni) * (KC / 2) + k2];
                acc[ni][0] += a.x * wr0.x + a.y * wr1.x + xx.x * wt0.x + xx.y * wt1.x;
                acc[ni][1] += a.x * wr0.y + a.y * wr1.y + xx.x * wt0.y + xx.y * wt1.y;
                acc[ni][2] += a.x * wr0.z + a.y * wr1.z + xx.x * wt0.z + xx.y * wt1.z;
                acc[ni][3] += a.x * wr0.w + a.y * wr1.w + xx.x * wt0.w + xx.y * wt1.w;
            }
        }
    }

    int o0 = to * 4;
    float4 bias = *(const float4*)&b_rel[o0];
#pragma unroll
    for (int ni = 0; ni < 4; ++ni) {
        int node = node0 + tn * 4 + ni;
        if (node >= N_NODES) continue;
        float4 v;
        v.x = fmaxf(acc[ni][0] + bias.x, 0.f);
        v.y = fmaxf(acc[ni][1] + bias.y, 0.f);
        v.z = fmaxf(acc[ni][2] + bias.z, 0.f);
        v.w = fmaxf(acc[ni][3] + bias.w, 0.f);
        *(float4*)&out[(size_t)node * D + o0] = v;
    }
}

__global__ __launch_bounds__(128) void gemm_fallback_kernel(const float* __restrict__ x,
                                                            const float* __restrict__ Wrel,
                                                            const float* __restrict__ Wroot,
                                                            const float* __restrict__ b_rel,
                                                            float* __restrict__ out) {
    __shared__ float rowA[D];
    __shared__ float rowX[D];
    int node = blockIdx.x;
    int o = threadIdx.x;
    rowA[o] = out[(size_t)node * D + o];
    rowX[o] = x[(size_t)node * D + o];
    __syncthreads();
    float acc = b_rel[o];
    const float4* wr = (const float4*)&Wrel[o * D];
    const float4* wt = (const float4*)&Wroot[o * D];
#pragma unroll 8
    for (int k4 = 0; k4 < D / 4; ++k4) {
        float4 w = wr[k4], u = wt[k4];
        const float* a = &rowA[k4 * 4];
        const float* xx = &rowX[k4 * 4];
        acc += a[0] * w.x + a[1] * w.y + a[2] * w.z + a[3] * w.w
             + xx[0] * u.x + xx[1] * u.y + xx[2] * u.z + xx[3] * u.w;
    }
    __syncthreads();
    out[(size_t)node * D + o] = fmaxf(acc, 0.f);
}

extern "C" void kernel_launch(void* const* d_in, const int* in_sizes, int n_in,
                              void* d_out, int out_size, void* d_ws, size_t ws_size,
                              hipStream_t stream) {
    const float* x      = (const float*)d_in[0];
    const int*   ei     = (const int*)d_in[1];
    const float* W_rel  = (const float*)d_in[2];
    const float* b_rel  = (const float*)d_in[3];
    const float* W_root = (const float*)d_in[4];
    float*       out    = (float*)d_out;

    // Full-tier ws layout (16 B aligned):
    //   flag(16) | pwc 64K | xb 12.8M | deg 200K | offs 200K | csr 3.2M  (~16.5 MB)
    char* p = (char*)d_ws;
    size_t o0 = 16;
    int*            flag  = (int*)p;
    unsigned short* pwc   = (unsigned short*)(p + o0);  o0 += (size_t)PACK_N * 2;
    unsigned short* xb    = (unsigned short*)(p + o0);  o0 += (size_t)N_NODES * D * 2;
    int*            deg   = (int*)(p + o0);             o0 += (size_t)N_NODES * 4;
    int*            offs  = (int*)(p + o0);             o0 += ((size_t)N_NODES + 1) * 4 + 12;
    o0 &= ~15ull;
    int*            csr   = (int*)(p + o0);             o0 += (size_t)N_EDGES * 4;
    const size_t need_full = o0;

    // Mid-tier layout: flag | pwrel 64K | pwroot 64K | deg | offs | csr
    size_t m0 = 16;
    float* m_pwrel  = (float*)(p + m0);  m0 += (size_t)D * D * 4;
    float* m_pwroot = (float*)(p + m0);  m0 += (size_t)D * D * 4;
    int*   m_deg    = (int*)(p + m0);    m0 += (size_t)N_NODES * 4;
    int*   m_offs   = (int*)(p + m0);    m0 += ((size_t)N_NODES + 1) * 4 + 12;
    m0 &= ~15ull;
    int*   m_csr    = (int*)(p + m0);    m0 += (size_t)N_EDGES * 4;
    const size_t need_mid = m0;
    const size_t need_pw  = 16 + 2 * (size_t)D * D * 4;

    const int eb4 = (N_EDGES / 4 + 255) / 256;   // 782 blocks for 4-edge kernels

    if (ws_size >= need_full) {
        const int prep_total = CVT_N + PACK_N + N_NODES;
        prep_kernel<<<(prep_total + 255) / 256, 256, 0, stream>>>(
            (const float2*)x, (ushort2*)xb, W_rel, W_root, pwc, deg);
        hist_kernel<<<eb4, 256, 0, stream>>>(ei, deg);
        scan_kernel<<<1, 1024, 0, stream>>>(deg, offs, deg);   // deg -> cursor in place
        reorder_kernel<<<eb4, 256, 0, stream>>>(ei, deg, csr);
        GraphConvLayer_55783035240593_kernel<<<(N_NODES + 63) / 64, 256, 0, stream>>>(
            (const ushort2*)xb, xb, csr, offs, pwc, b_rel, out);
    } else if (ws_size >= need_mid) {
        pack_w_kernel<<<64, 256, 0, stream>>>(W_rel, m_pwrel);
        pack_w_kernel<<<64, 256, 0, stream>>>(W_root, m_pwroot);
        zero_f4_kernel<<<(N_NODES / 4 + 255) / 256, 256, 0, stream>>>((float4*)m_deg,
                                                                      N_NODES / 4);
        hist_kernel<<<eb4, 256, 0, stream>>>(ei, m_deg);
        scan_kernel<<<1, 1024, 0, stream>>>(m_deg, m_offs, m_deg);
        reorder_kernel<<<eb4, 256, 0, stream>>>(ei, m_deg, m_csr);
        gather_kernel<<<N_NODES / 4, 256, 0, stream>>>((const float2*)x, m_csr,
                                                       m_offs, (float2*)out);
        gemm_f32_kernel<<<(N_NODES + NPB - 1) / NPB, 256, 0, stream>>>(
            (const float2*)x, m_pwrel, m_pwroot, b_rel, out);
    } else {
        bool have_flag = ws_size >= 16;
        bool have_pw   = ws_size >= need_pw;
        if (have_flag) detect_kernel<<<1, 64, 0, stream>>>(ei, flag);
        if (have_pw) {
            pack_w_kernel<<<64, 256, 0, stream>>>(W_rel, m_pwrel);
            pack_w_kernel<<<64, 256, 0, stream>>>(W_root, m_pwroot);
        }
        int n4 = N_NODES * D / 4;
        zero_f4_kernel<<<(n4 + 255) / 256, 256, 0, stream>>>((float4*)out, n4);
        scatter_kernel<<<N_EDGES / 4, 256, 0, stream>>>((const float2*)x, ei,
                                                        have_flag ? flag : nullptr, out);
        if (have_pw)
            gemm_f32_kernel<<<(N_NODES + NPB - 1) / NPB, 256, 0, stream>>>(
                (const float2*)x, m_pwrel, m_pwroot, b_rel, out);
        else
            gemm_fallback_kernel<<<N_NODES, 128, 0, stream>>>(x, W_rel, W_root, b_rel, out);
    }
}

// Round 9
// 263.252 us; speedup vs baseline: 1.0729x; 1.0729x over previous
//
#include <hip/hip_runtime.h>
#include <hip/hip_bf16.h>

// GraphConv (PyG, aggr='add') + ReLU on MI355X — fp32 in/out, bf16 internals.
//   out = relu( segment_sum(x[src] -> dst) @ W_rel^T + b_rel + x @ W_root^T )
// N=50000, E=800000, D=128.
//
// Round 9: round-8 fusion collapsed gather parallelism (782 blocks -> 3128
// waves, 16 serial nodes/wave, occupancy 26%). v2: 16 nodes/block, 3125
// blocks (12500 gather waves = full occupancy), 8 row-loads in flight,
// MFMA n0-groups split across the 4 waves. NT stores in reorder reverted
// (they bypassed+evicted L2 lines the gather immediately re-reads).

#define N_NODES 50000
#define N_EDGES 800000
#define D 128
#define NPB 32      // nodes per fp32-gemm block (mid tier)
#define KC 32       // k per chunk (mid tier)
#define SROW 136    // LDS agg-row stride (ushorts); 272 B rows, 16B-aligned, 2-way banks

#define CVT_N  (N_NODES * (D / 2))   // 3,200,000 ushort2 conversions
#define PACK_N (8 * 8 * 64 * 8)      // 32,768 packed B-fragment elements

typedef __attribute__((ext_vector_type(8))) short short8;   // 8 bf16 = 4 VGPRs
typedef __attribute__((ext_vector_type(4))) float floatx4;

__device__ __forceinline__ float bf2f(unsigned short u) {
    return __uint_as_float((unsigned int)u << 16);
}
__device__ __forceinline__ unsigned short f2bf(float f) {
    __hip_bfloat16 h = __float2bfloat16(f);
    return *(unsigned short*)&h;
}

// int64 node-id array => every odd int32 word is 0 (ids < 50000).
// Must run with all 64 lanes active (call before any early return).
__device__ __forceinline__ int wave_detect_i64(const int* __restrict__ ei) {
    int lane = threadIdx.x & 63;
    int v = ei[2 * lane + 1];
    return __ballot(v == 0) == ~0ull;
}

// ---------------- utility ----------------
__global__ __launch_bounds__(256) void zero_f4_kernel(float4* __restrict__ p, int n4) {
    int i = blockIdx.x * 256 + threadIdx.x;
    if (i < n4) p[i] = make_float4(0.f, 0.f, 0.f, 0.f);
}

// flag-based detect kept only for the low-tier scatter fallback
__global__ void detect_kernel(const int* __restrict__ ei, int* __restrict__ flag) {
    if (threadIdx.x == 0 && blockIdx.x == 0) {
        int any = 0;
        for (int i = 0; i < 64; ++i) any |= ei[2 * i + 1];
        flag[0] = (any == 0) ? 1 : 0;
    }
}

// ---------------- fused prep: cvt_x + pack_frag + zero deg ----------------
__global__ __launch_bounds__(256) void prep_kernel(const float2* __restrict__ x2,
                                                   ushort2* __restrict__ xb2,
                                                   const float* __restrict__ Wrel,
                                                   const float* __restrict__ Wroot,
                                                   unsigned short* __restrict__ pwc,
                                                   int* __restrict__ deg) {
    int i = blockIdx.x * 256 + threadIdx.x;
    if (i < CVT_N) {
        float2 f = x2[i];
        xb2[i] = make_ushort2(f2bf(f.x), f2bf(f.y));
    } else if (i < CVT_N + PACK_N) {
        // pwc[((t*8+n0)*64+lane)*8+j] = W_cat[n0*16+(lane&15)][t*32+(lane>>4)*8+j]
        int idx  = i - CVT_N;
        int j    = idx & 7;
        int lane = (idx >> 3) & 63;
        int n0   = (idx >> 9) & 7;
        int t    = idx >> 12;
        int n = n0 * 16 + (lane & 15);
        int k = t * 32 + (lane >> 4) * 8 + j;
        float w = (k < D) ? Wrel[n * D + k] : Wroot[n * D + (k - D)];
        pwc[idx] = f2bf(w);
    } else if (i < CVT_N + PACK_N + N_NODES) {
        deg[i - CVT_N - PACK_N] = 0;
    }
}

// ---------------- CSR build (4 edges/thread for atomic MLP) ----------------
__global__ __launch_bounds__(256) void hist_kernel(const int* __restrict__ ei,
                                                   int* __restrict__ deg) {
    int i64 = wave_detect_i64(ei);
    int base = (blockIdx.x * 256 + threadIdx.x) * 4;
    if (base >= N_EDGES) return;
    int d0, d1, d2, d3;
    if (i64) {
        int4 a = *(const int4*)&ei[2 * N_EDGES + 2 * base];
        int4 b = *(const int4*)&ei[2 * N_EDGES + 2 * base + 4];
        d0 = a.x; d1 = a.z; d2 = b.x; d3 = b.z;
    } else {
        int4 v = *(const int4*)&ei[N_EDGES + base];
        d0 = v.x; d1 = v.y; d2 = v.z; d3 = v.w;
    }
    if ((unsigned)d0 < N_NODES) atomicAdd(&deg[d0], 1);
    if ((unsigned)d1 < N_NODES) atomicAdd(&deg[d1], 1);
    if ((unsigned)d2 < N_NODES) atomicAdd(&deg[d2], 1);
    if ((unsigned)d3 < N_NODES) atomicAdd(&deg[d3], 1);
}

__device__ __forceinline__ int wave_iscan(int v, int lane) {
#pragma unroll
    for (int off = 1; off < 64; off <<= 1) {
        int u = __shfl_up(v, off, 64);
        if (lane >= off) v += u;
    }
    return v;
}

// Single-block scan. offsets[0]=0, offsets[i+1]=incl sum; cursor[i]=excl sum.
__global__ __launch_bounds__(1024) void scan_kernel(const int* __restrict__ deg,
                                                    int* __restrict__ offsets,
                                                    int* __restrict__ cursor) {
    __shared__ int wsum[16];
    __shared__ int base_s;
    int t = threadIdx.x, lane = t & 63, w = t >> 6;
    if (t == 0) { base_s = 0; offsets[0] = 0; }
    __syncthreads();
    for (int c0 = 0; c0 < N_NODES; c0 += 1024) {
        int idx = c0 + t;
        int v = (idx < N_NODES) ? deg[idx] : 0;
        int inc = wave_iscan(v, lane);
        if (lane == 63) wsum[w] = inc;
        __syncthreads();
        if (w == 0) {
            int s = (lane < 16) ? wsum[lane] : 0;
            int si = wave_iscan(s, lane);
            if (lane < 16) wsum[lane] = si - s;   // exclusive wave base
        }
        __syncthreads();
        int tot = base_s + wsum[w] + inc;
        if (idx < N_NODES) {
            offsets[idx + 1] = tot;
            cursor[idx] = tot - v;                // exclusive prefix
        }
        __syncthreads();
        if (t == 1023) base_s = tot;
        __syncthreads();
    }
}

// 4 edges/thread: 4 independent returning atomics in flight; plain stores
// (csr_src stays L2-resident for the gather that follows).
__global__ __launch_bounds__(256) void reorder_kernel(const int* __restrict__ ei,
                                                      int* __restrict__ cursor,
                                                      int* __restrict__ csr_src) {
    int i64 = wave_detect_i64(ei);
    int base = (blockIdx.x * 256 + threadIdx.x) * 4;
    if (base >= N_EDGES) return;
    int s0, s1, s2, s3, d0, d1, d2, d3;
    if (i64) {
        int4 a = *(const int4*)&ei[2 * base];
        int4 b = *(const int4*)&ei[2 * base + 4];
        s0 = a.x; s1 = a.z; s2 = b.x; s3 = b.z;
        int4 c = *(const int4*)&ei[2 * N_EDGES + 2 * base];
        int4 e = *(const int4*)&ei[2 * N_EDGES + 2 * base + 4];
        d0 = c.x; d1 = c.z; d2 = e.x; d3 = e.z;
    } else {
        int4 sv = *(const int4*)&ei[base];
        int4 dv = *(const int4*)&ei[N_EDGES + base];
        s0 = sv.x; s1 = sv.y; s2 = sv.z; s3 = sv.w;
        d0 = dv.x; d1 = dv.y; d2 = dv.z; d3 = dv.w;
    }
    bool v0 = (unsigned)s0 < N_NODES && (unsigned)d0 < N_NODES;
    bool v1 = (unsigned)s1 < N_NODES && (unsigned)d1 < N_NODES;
    bool v2 = (unsigned)s2 < N_NODES && (unsigned)d2 < N_NODES;
    bool v3 = (unsigned)s3 < N_NODES && (unsigned)d3 < N_NODES;
    int p0 = v0 ? atomicAdd(&cursor[d0], 1) : 0;   // 4 independent round-trips
    int p1 = v1 ? atomicAdd(&cursor[d1], 1) : 0;
    int p2 = v2 ? atomicAdd(&cursor[d2], 1) : 0;
    int p3 = v3 ? atomicAdd(&cursor[d3], 1) : 0;
    if (v0) csr_src[p0] = s0;
    if (v1) csr_src[p1] = s1;
    if (v2) csr_src[p2] = s2;
    if (v3) csr_src[p3] = s3;
}

// ---------------- fused gather + MFMA GEMM + bias + ReLU (v2) ----------------
// Block = 4 waves = 16 nodes (grid 3125 -> 12500 gather waves, full occupancy).
// Gather: wave w handles nodes w*4..w*4+3, 8 independent row loads in flight,
// result rows in LDS (stride 136 ushorts -> aligned b128, 2-way = free).
// MFMA: each wave computes 2 of the 8 n0 output-column groups for all 16
// nodes (16 MFMAs/wave). A from LDS (agg) and global (x); B pre-packed.
// Layouts (verified): A[m=lane&15][k=quad*8+j], D: col=lane&15, row=quad*4+reg.
__global__ __launch_bounds__(256) void GraphConvLayer_55783035240593_kernel(
        const ushort2* __restrict__ xb2,
        const unsigned short* __restrict__ xb,
        const int* __restrict__ csr_src,
        const int* __restrict__ offsets,
        const unsigned short* __restrict__ pwc,
        const float* __restrict__ b_rel,
        float* __restrict__ out) {
    __shared__ unsigned short sA[16 * SROW];   // 4352 B
    int wid  = threadIdx.x >> 6;
    int lane = threadIdx.x & 63;
    int node0 = blockIdx.x * 16;               // 50000 = 3125 * 16, exact

    // ---- gather phase: 4 nodes per wave ----
    for (int li = 0; li < 4; ++li) {
        int node = node0 + wid * 4 + li;
        int beg = offsets[node], end = offsets[node + 1];
        float ax = 0.f, ay = 0.f;
        for (int e = beg; e < end; e += 64) {
            int cnt = end - e;
            if (cnt > 64) cnt = 64;
            int myidx = (lane < cnt) ? csr_src[e + lane] : 0;
            for (int j = 0; j < cnt; j += 8) {
                int s0 = __shfl(myidx, j);
                int s1 = __shfl(myidx, j + 1);   // lanes >= cnt hold 0 (valid row)
                int s2 = __shfl(myidx, j + 2);
                int s3 = __shfl(myidx, j + 3);
                int s4 = __shfl(myidx, j + 4);
                int s5 = __shfl(myidx, j + 5);
                int s6 = __shfl(myidx, j + 6);
                int s7 = __shfl(myidx, j + 7);
                ushort2 u0 = xb2[(size_t)s0 * (D / 2) + lane];
                ushort2 u1 = xb2[(size_t)s1 * (D / 2) + lane];
                ushort2 u2 = xb2[(size_t)s2 * (D / 2) + lane];
                ushort2 u3 = xb2[(size_t)s3 * (D / 2) + lane];
                ushort2 u4 = xb2[(size_t)s4 * (D / 2) + lane];
                ushort2 u5 = xb2[(size_t)s5 * (D / 2) + lane];
                ushort2 u6 = xb2[(size_t)s6 * (D / 2) + lane];
                ushort2 u7 = xb2[(size_t)s7 * (D / 2) + lane];
                float m1 = (j + 1 < cnt) ? 1.f : 0.f;
                float m2 = (j + 2 < cnt) ? 1.f : 0.f;
                float m3 = (j + 3 < cnt) ? 1.f : 0.f;
                float m4 = (j + 4 < cnt) ? 1.f : 0.f;
                float m5 = (j + 5 < cnt) ? 1.f : 0.f;
                float m6 = (j + 6 < cnt) ? 1.f : 0.f;
                float m7 = (j + 7 < cnt) ? 1.f : 0.f;
                ax += bf2f(u0.x) + m1 * bf2f(u1.x) + m2 * bf2f(u2.x) + m3 * bf2f(u3.x)
                    + m4 * bf2f(u4.x) + m5 * bf2f(u5.x) + m6 * bf2f(u6.x) + m7 * bf2f(u7.x);
                ay += bf2f(u0.y) + m1 * bf2f(u1.y) + m2 * bf2f(u2.y) + m3 * bf2f(u3.y)
                    + m4 * bf2f(u4.y) + m5 * bf2f(u5.y) + m6 * bf2f(u6.y) + m7 * bf2f(u7.y);
            }
        }
        *(ushort2*)&sA[(wid * 4 + li) * SROW + 2 * lane] =
            make_ushort2(f2bf(ax), f2bf(ay));
    }
    __syncthreads();

    // ---- MFMA phase: wave wid computes n0 = 2*wid, 2*wid+1 ----
    int m = lane & 15, quad = lane >> 4;
    const unsigned short* arow = &sA[m * SROW + quad * 8];
    const unsigned short* xrow = xb + (size_t)(node0 + m) * D + quad * 8;

    floatx4 acc0 = (floatx4){0.f, 0.f, 0.f, 0.f};
    floatx4 acc1 = (floatx4){0.f, 0.f, 0.f, 0.f};
#pragma unroll
    for (int t = 0; t < 8; ++t) {
        short8 afrag = (t < 4) ? *(const short8*)(arow + t * 32)
                               : *(const short8*)(xrow + (t - 4) * 32);
        const unsigned short* bb = pwc + ((size_t)(t * 8 + wid * 2) * 64 + lane) * 8;
        short8 b0 = *(const short8*)bb;
        short8 b1 = *(const short8*)(bb + 64 * 8);
        acc0 = __builtin_amdgcn_mfma_f32_16x16x32_bf16(afrag, b0, acc0, 0, 0, 0);
        acc1 = __builtin_amdgcn_mfma_f32_16x16x32_bf16(afrag, b1, acc1, 0, 0, 0);
    }

#pragma unroll
    for (int q = 0; q < 2; ++q) {
        floatx4 a = q ? acc1 : acc0;
        int n = (wid * 2 + q) * 16 + m;
        float bias = b_rel[n];
#pragma unroll
        for (int r = 0; r < 4; ++r) {
            int node = node0 + quad * 4 + r;
            out[(size_t)node * D + n] = fmaxf(a[r] + bias, 0.f);
        }
    }
}

// ---------------- mid tier: fp32 CSR + VALU GEMM ----------------
__global__ __launch_bounds__(256) void pack_w_kernel(const float* __restrict__ W,
                                                     float* __restrict__ pw) {
    int idx = blockIdx.x * 256 + threadIdx.x;
    if (idx >= D * D) return;
    int o = idx >> 7, k = idx & 127;
    pw[k * D + o] = W[o * D + k];
}

__global__ __launch_bounds__(256) void gather_kernel(const float2* __restrict__ x2,
                                                     const int* __restrict__ csr_src,
                                                     const int* __restrict__ offsets,
                                                     float2* __restrict__ agg2) {
    int node = blockIdx.x * 4 + (threadIdx.x >> 6);
    int lane = threadIdx.x & 63;
    if (node >= N_NODES) return;
    int beg = offsets[node], end = offsets[node + 1];
    float2 acc = make_float2(0.f, 0.f);
    for (int e = beg; e < end; ++e) {
        int s = csr_src[e];
        float2 f = x2[(size_t)s * (D / 2) + lane];
        acc.x += f.x;
        acc.y += f.y;
    }
    agg2[(size_t)node * (D / 2) + lane] = acc;
}

__global__ __launch_bounds__(256) void scatter_kernel(const float2* __restrict__ x2,
                                                      const int* __restrict__ ei,
                                                      const int* __restrict__ flag,
                                                      float* __restrict__ agg) {
    int wave = threadIdx.x >> 6;
    int lane = threadIdx.x & 63;
    int e = blockIdx.x * 4 + wave;
    if (e >= N_EDGES) return;
    int i64 = flag ? flag[0] : 0;
    int s, d;
    if (i64) { s = ei[2 * e]; d = ei[2 * N_EDGES + 2 * e]; }
    else     { s = ei[e];     d = ei[N_EDGES + e]; }
    if ((unsigned)s >= N_NODES || (unsigned)d >= N_NODES) return;
    float2 f = x2[(size_t)s * (D / 2) + lane];
    atomicAdd(&agg[(size_t)d * D + 2 * lane + 0], f.x);
    atomicAdd(&agg[(size_t)d * D + 2 * lane + 1], f.y);
}

__global__ __launch_bounds__(256) void gemm_f32_kernel(
        const float2* __restrict__ x2,
        const float* __restrict__ pwrel,
        const float* __restrict__ pwroot,
        const float* __restrict__ b_rel,
        float* __restrict__ out) {
    __shared__ float sWrel[KC * D];
    __shared__ float sWroot[KC * D];
    __shared__ float2 sAm[NPB * (KC / 2)];
    __shared__ float2 sXm[NPB * (KC / 2)];

    int t = threadIdx.x;
    int node0 = blockIdx.x * NPB;
    int tn = t >> 5;
    int to = t & 31;

    float acc[4][4];
#pragma unroll
    for (int a = 0; a < 4; ++a)
#pragma unroll
        for (int b = 0; b < 4; ++b) acc[a][b] = 0.0f;

    for (int c = 0; c < 4; ++c) {
        __syncthreads();
#pragma unroll
        for (int r = 0; r < 4; ++r) {
            int i = r * 256 + t;
            ((float4*)sWrel)[i]  = ((const float4*)(pwrel  + c * KC * D))[i];
            ((float4*)sWroot)[i] = ((const float4*)(pwroot + c * KC * D))[i];
        }
#pragma unroll
        for (int r = 0; r < 2; ++r) {
            int i = r * 256 + t;
            int n = i >> 4, k2 = i & 15;
            int node = node0 + n;
            float2 av = make_float2(0.f, 0.f), xv = make_float2(0.f, 0.f);
            if (node < N_NODES) {
                av = ((const float2*)out)[(size_t)node * (D / 2) + c * (KC / 2) + k2];
                xv = x2[(size_t)node * (D / 2) + c * (KC / 2) + k2];
            }
            sAm[i] = av;
            sXm[i] = xv;
        }
        __syncthreads();

#pragma unroll
        for (int k2 = 0; k2 < KC / 2; ++k2) {
            float4 wr0 = *(const float4*)&sWrel[(2 * k2 + 0) * D + to * 4];
            float4 wr1 = *(const float4*)&sWrel[(2 * k2 + 1) * D + to * 4];
            float4 wt0 = *(const float4*)&sWroot[(2 * k2 + 0) * D + to * 4];
            float4 wt1 = *(const float4*)&sWroot[(2 * k2 + 1) * D + to * 4];
#pragma unroll
            for (int ni = 0; ni < 4; ++ni) {
                float2 a  = sAm[(tn * 4 + ni) * (KC / 2) + k2];
                float2 xx = sXm[(tn * 4 + ni) * (KC / 2) + k2];
                acc[ni][0] += a.x * wr0.x + a.y * wr1.x + xx.x * wt0.x + xx.y * wt1.x;
                acc[ni][1] += a.x * wr0.y + a.y * wr1.y + xx.x * wt0.y + xx.y * wt1.y;
                acc[ni][2] += a.x * wr0.z + a.y * wr1.z + xx.x * wt0.z + xx.y * wt1.z;
                acc[ni][3] += a.x * wr0.w + a.y * wr1.w + xx.x * wt0.w + xx.y * wt1.w;
            }
        }
    }

    int o0 = to * 4;
    float4 bias = *(const float4*)&b_rel[o0];
#pragma unroll
    for (int ni = 0; ni < 4; ++ni) {
        int node = node0 + tn * 4 + ni;
        if (node >= N_NODES) continue;
        float4 v;
        v.x = fmaxf(acc[ni][0] + bias.x, 0.f);
        v.y = fmaxf(acc[ni][1] + bias.y, 0.f);
        v.z = fmaxf(acc[ni][2] + bias.z, 0.f);
        v.w = fmaxf(acc[ni][3] + bias.w, 0.f);
        *(float4*)&out[(size_t)node * D + o0] = v;
    }
}

__global__ __launch_bounds__(128) void gemm_fallback_kernel(const float* __restrict__ x,
                                                            const float* __restrict__ Wrel,
                                                            const float* __restrict__ Wroot,
                                                            const float* __restrict__ b_rel,
                                                            float* __restrict__ out) {
    __shared__ float rowA[D];
    __shared__ float rowX[D];
    int node = blockIdx.x;
    int o = threadIdx.x;
    rowA[o] = out[(size_t)node * D + o];
    rowX[o] = x[(size_t)node * D + o];
    __syncthreads();
    float acc = b_rel[o];
    const float4* wr = (const float4*)&Wrel[o * D];
    const float4* wt = (const float4*)&Wroot[o * D];
#pragma unroll 8
    for (int k4 = 0; k4 < D / 4; ++k4) {
        float4 w = wr[k4], u = wt[k4];
        const float* a = &rowA[k4 * 4];
        const float* xx = &rowX[k4 * 4];
        acc += a[0] * w.x + a[1] * w.y + a[2] * w.z + a[3] * w.w
             + xx[0] * u.x + xx[1] * u.y + xx[2] * u.z + xx[3] * u.w;
    }
    __syncthreads();
    out[(size_t)node * D + o] = fmaxf(acc, 0.f);
}

extern "C" void kernel_launch(void* const* d_in, const int* in_sizes, int n_in,
                              void* d_out, int out_size, void* d_ws, size_t ws_size,
                              hipStream_t stream) {
    const float* x      = (const float*)d_in[0];
    const int*   ei     = (const int*)d_in[1];
    const float* W_rel  = (const float*)d_in[2];
    const float* b_rel  = (const float*)d_in[3];
    const float* W_root = (const float*)d_in[4];
    float*       out    = (float*)d_out;

    // Full-tier ws layout (16 B aligned):
    //   flag(16) | pwc 64K | xb 12.8M | deg 200K | offs 200K | csr 3.2M  (~16.5 MB)
    char* p = (char*)d_ws;
    size_t o0 = 16;
    int*            flag  = (int*)p;
    unsigned short* pwc   = (unsigned short*)(p + o0);  o0 += (size_t)PACK_N * 2;
    unsigned short* xb    = (unsigned short*)(p + o0);  o0 += (size_t)N_NODES * D * 2;
    int*            deg   = (int*)(p + o0);             o0 += (size_t)N_NODES * 4;
    int*            offs  = (int*)(p + o0);             o0 += ((size_t)N_NODES + 1) * 4 + 12;
    o0 &= ~15ull;
    int*            csr   = (int*)(p + o0);             o0 += (size_t)N_EDGES * 4;
    const size_t need_full = o0;

    // Mid-tier layout: flag | pwrel 64K | pwroot 64K | deg | offs | csr
    size_t m0 = 16;
    float* m_pwrel  = (float*)(p + m0);  m0 += (size_t)D * D * 4;
    float* m_pwroot = (float*)(p + m0);  m0 += (size_t)D * D * 4;
    int*   m_deg    = (int*)(p + m0);    m0 += (size_t)N_NODES * 4;
    int*   m_offs   = (int*)(p + m0);    m0 += ((size_t)N_NODES + 1) * 4 + 12;
    m0 &= ~15ull;
    int*   m_csr    = (int*)(p + m0);    m0 += (size_t)N_EDGES * 4;
    const size_t need_mid = m0;
    const size_t need_pw  = 16 + 2 * (size_t)D * D * 4;

    const int eb4 = (N_EDGES / 4 + 255) / 256;   // 782 blocks for 4-edge kernels

    if (ws_size >= need_full) {
        const int prep_total = CVT_N + PACK_N + N_NODES;
        prep_kernel<<<(prep_total + 255) / 256, 256, 0, stream>>>(
            (const float2*)x, (ushort2*)xb, W_rel, W_root, pwc, deg);
        hist_kernel<<<eb4, 256, 0, stream>>>(ei, deg);
        scan_kernel<<<1, 1024, 0, stream>>>(deg, offs, deg);   // deg -> cursor in place
        reorder_kernel<<<eb4, 256, 0, stream>>>(ei, deg, csr);
        GraphConvLayer_55783035240593_kernel<<<N_NODES / 16, 256, 0, stream>>>(
            (const ushort2*)xb, xb, csr, offs, pwc, b_rel, out);
    } else if (ws_size >= need_mid) {
        pack_w_kernel<<<64, 256, 0, stream>>>(W_rel, m_pwrel);
        pack_w_kernel<<<64, 256, 0, stream>>>(W_root, m_pwroot);
        zero_f4_kernel<<<(N_NODES / 4 + 255) / 256, 256, 0, stream>>>((float4*)m_deg,
                                                                      N_NODES / 4);
        hist_kernel<<<eb4, 256, 0, stream>>>(ei, m_deg);
        scan_kernel<<<1, 1024, 0, stream>>>(m_deg, m_offs, m_deg);
        reorder_kernel<<<eb4, 256, 0, stream>>>(ei, m_deg, m_csr);
        gather_kernel<<<N_NODES / 4, 256, 0, stream>>>((const float2*)x, m_csr,
                                                       m_offs, (float2*)out);
        gemm_f32_kernel<<<(N_NODES + NPB - 1) / NPB, 256, 0, stream>>>(
            (const float2*)x, m_pwrel, m_pwroot, b_rel, out);
    } else {
        bool have_flag = ws_size >= 16;
        bool have_pw   = ws_size >= need_pw;
        if (have_flag) detect_kernel<<<1, 64, 0, stream>>>(ei, flag);
        if (have_pw) {
            pack_w_kernel<<<64, 256, 0, stream>>>(W_rel, m_pwrel);
            pack_w_kernel<<<64, 256, 0, stream>>>(W_root, m_pwroot);
        }
        int n4 = N_NODES * D / 4;
        zero_f4_kernel<<<(n4 + 255) / 256, 256, 0, stream>>>((float4*)out, n4);
        scatter_kernel<<<N_EDGES / 4, 256, 0, stream>>>((const float2*)x, ei,
                                                        have_flag ? flag : nullptr, out);
        if (have_pw)
            gemm_f32_kernel<<<(N_NODES + NPB - 1) / NPB, 256, 0, stream>>>(
                (const float2*)x, m_pwrel, m_pwroot, b_rel, out);
        else
            gemm_fallback_kernel<<<N_NODES, 128, 0, stream>>>(x, W_rel, W_root, b_rel, out);
    }
}

// Round 10
// 172.296 us; speedup vs baseline: 1.6393x; 1.5279x over previous
//
#include <hip/hip_runtime.h>
#include <hip/hip_bf16.h>

// GraphConv (PyG, aggr='add') + ReLU on MI355X — fp32 in/out, bf16 internals.
//   out = relu( segment_sum(x[src] -> dst) @ W_rel^T + b_rel + x @ W_root^T )
// N=50000, E=800000, D=128.
//
// Round 10: the single-block scan (~16 waves on ONE CU, 49 serial chunks) and
// the histogram were costing ~90-120 µs combined. Replaced exact CSR with a
// PADDED CSR: 48 slots/node + overflow list (correct for any input; empty for
// this dataset). Pipeline is now 3 kernels: prep -> append -> fused
// gather+MFMA. No hist, no scan, no reorder.

#define N_NODES 50000
#define N_EDGES 800000
#define D 128
#define SLOTS 48    // padded-CSR slots per node (deg ~Poisson(16))
#define NPB 32      // nodes per fp32-gemm block (mid tier)
#define KC 32       // k per chunk (mid tier)
#define SROW 136    // LDS agg-row stride (ushorts); 272 B rows, 2-way banks = free

#define CVT_N  (N_NODES * (D / 2))   // 3,200,000 ushort2 conversions
#define PACK_N (8 * 8 * 64 * 8)      // 32,768 packed B-fragment elements

typedef __attribute__((ext_vector_type(8))) short short8;   // 8 bf16 = 4 VGPRs
typedef __attribute__((ext_vector_type(4))) float floatx4;

__device__ __forceinline__ float bf2f(unsigned short u) {
    return __uint_as_float((unsigned int)u << 16);
}
__device__ __forceinline__ unsigned short f2bf(float f) {
    __hip_bfloat16 h = __float2bfloat16(f);
    return *(unsigned short*)&h;
}

// int64 node-id array => every odd int32 word is 0 (ids < 50000).
// Must run with all 64 lanes active (call before any early return).
__device__ __forceinline__ int wave_detect_i64(const int* __restrict__ ei) {
    int lane = threadIdx.x & 63;
    int v = ei[2 * lane + 1];
    return __ballot(v == 0) == ~0ull;
}

// ---------------- utility ----------------
__global__ __launch_bounds__(256) void zero_f4_kernel(float4* __restrict__ p, int n4) {
    int i = blockIdx.x * 256 + threadIdx.x;
    if (i < n4) p[i] = make_float4(0.f, 0.f, 0.f, 0.f);
}

// flag-based detect kept only for the low-tier scatter fallback
__global__ void detect_kernel(const int* __restrict__ ei, int* __restrict__ flag) {
    if (threadIdx.x == 0 && blockIdx.x == 0) {
        int any = 0;
        for (int i = 0; i < 64; ++i) any |= ei[2 * i + 1];
        flag[0] = (any == 0) ? 1 : 0;
    }
}

// ---------------- fused prep: cvt_x + pack_frag + zero cnt/ovf_cnt ----------------
__global__ __launch_bounds__(256) void prep_kernel(const float2* __restrict__ x2,
                                                   ushort2* __restrict__ xb2,
                                                   const float* __restrict__ Wrel,
                                                   const float* __restrict__ Wroot,
                                                   unsigned short* __restrict__ pwc,
                                                   int* __restrict__ cnt) {
    int i = blockIdx.x * 256 + threadIdx.x;
    if (i < CVT_N) {
        float2 f = x2[i];
        xb2[i] = make_ushort2(f2bf(f.x), f2bf(f.y));
    } else if (i < CVT_N + PACK_N) {
        // pwc[((t*8+n0)*64+lane)*8+j] = W_cat[n0*16+(lane&15)][t*32+(lane>>4)*8+j]
        int idx  = i - CVT_N;
        int j    = idx & 7;
        int lane = (idx >> 3) & 63;
        int n0   = (idx >> 9) & 7;
        int t    = idx >> 12;
        int n = n0 * 16 + (lane & 15);
        int k = t * 32 + (lane >> 4) * 8 + j;
        float w = (k < D) ? Wrel[n * D + k] : Wroot[n * D + (k - D)];
        pwc[idx] = f2bf(w);
    } else if (i < CVT_N + PACK_N + N_NODES + 4) {
        cnt[i - CVT_N - PACK_N] = 0;   // cnt[0..N) and ovf_cnt (4 ints right after)
    }
}

// ---------------- padded-CSR append (4 edges/thread) ----------------
__global__ __launch_bounds__(256) void append_kernel(const int* __restrict__ ei,
                                                     int* __restrict__ cnt,
                                                     int* __restrict__ slots,
                                                     int* __restrict__ ovf_cnt,
                                                     int* __restrict__ ovf) {
    int i64 = wave_detect_i64(ei);
    int base = (blockIdx.x * 256 + threadIdx.x) * 4;
    if (base >= N_EDGES) return;
    int s0, s1, s2, s3, d0, d1, d2, d3;
    if (i64) {
        int4 a = *(const int4*)&ei[2 * base];
        int4 b = *(const int4*)&ei[2 * base + 4];
        s0 = a.x; s1 = a.z; s2 = b.x; s3 = b.z;
        int4 c = *(const int4*)&ei[2 * N_EDGES + 2 * base];
        int4 e = *(const int4*)&ei[2 * N_EDGES + 2 * base + 4];
        d0 = c.x; d1 = c.z; d2 = e.x; d3 = e.z;
    } else {
        int4 sv = *(const int4*)&ei[base];
        int4 dv = *(const int4*)&ei[N_EDGES + base];
        s0 = sv.x; s1 = sv.y; s2 = sv.z; s3 = sv.w;
        d0 = dv.x; d1 = dv.y; d2 = dv.z; d3 = dv.w;
    }
    bool v0 = (unsigned)s0 < N_NODES && (unsigned)d0 < N_NODES;
    bool v1 = (unsigned)s1 < N_NODES && (unsigned)d1 < N_NODES;
    bool v2 = (unsigned)s2 < N_NODES && (unsigned)d2 < N_NODES;
    bool v3 = (unsigned)s3 < N_NODES && (unsigned)d3 < N_NODES;
    int p0 = v0 ? atomicAdd(&cnt[d0], 1) : 0;   // 4 independent round-trips
    int p1 = v1 ? atomicAdd(&cnt[d1], 1) : 0;
    int p2 = v2 ? atomicAdd(&cnt[d2], 1) : 0;
    int p3 = v3 ? atomicAdd(&cnt[d3], 1) : 0;
    if (v0) { if (p0 < SLOTS) slots[d0 * SLOTS + p0] = s0;
              else { int o = atomicAdd(ovf_cnt, 1); ovf[2 * o] = d0; ovf[2 * o + 1] = s0; } }
    if (v1) { if (p1 < SLOTS) slots[d1 * SLOTS + p1] = s1;
              else { int o = atomicAdd(ovf_cnt, 1); ovf[2 * o] = d1; ovf[2 * o + 1] = s1; } }
    if (v2) { if (p2 < SLOTS) slots[d2 * SLOTS + p2] = s2;
              else { int o = atomicAdd(ovf_cnt, 1); ovf[2 * o] = d2; ovf[2 * o + 1] = s2; } }
    if (v3) { if (p3 < SLOTS) slots[d3 * SLOTS + p3] = s3;
              else { int o = atomicAdd(ovf_cnt, 1); ovf[2 * o] = d3; ovf[2 * o + 1] = s3; } }
}

// ---------------- fused gather + MFMA GEMM + bias + ReLU ----------------
// Block = 4 waves = 16 nodes (3125 blocks -> 12500 gather waves).
// Gather: wave w handles nodes w*4..w*4+3; one coalesced slot load (<=48),
// 8 independent row loads in flight; rare overflow entries scanned only if
// ovf_cnt > 0. Rows land in LDS (stride 136 -> 2-way = free).
// MFMA: wave wid computes n0 groups {2*wid, 2*wid+1} for all 16 nodes.
// Layouts (verified): A[m=lane&15][k=quad*8+j], D: col=lane&15, row=quad*4+reg.
__global__ __launch_bounds__(256) void GraphConvLayer_55783035240593_kernel(
        const ushort2* __restrict__ xb2,
        const unsigned short* __restrict__ xb,
        const int* __restrict__ cnt,
        const int* __restrict__ slots,
        const int* __restrict__ ovf_cnt,
        const int* __restrict__ ovf,
        const unsigned short* __restrict__ pwc,
        const float* __restrict__ b_rel,
        float* __restrict__ out) {
    __shared__ unsigned short sA[16 * SROW];   // 4352 B
    int wid  = threadIdx.x >> 6;
    int lane = threadIdx.x & 63;
    int node0 = blockIdx.x * 16;               // 50000 = 3125 * 16, exact
    int tov = ovf_cnt[0];                      // broadcast, L2-hot

    // ---- gather phase: 4 nodes per wave ----
    for (int li = 0; li < 4; ++li) {
        int node = node0 + wid * 4 + li;
        int kk = cnt[node];
        if (kk > SLOTS) kk = SLOTS;
        int myidx = (lane < kk) ? slots[node * SLOTS + lane] : 0;  // one coalesced load
        float ax = 0.f, ay = 0.f;
        for (int j = 0; j < kk; j += 8) {
            int s0 = __shfl(myidx, j);
            int s1 = __shfl(myidx, j + 1);   // lanes >= kk hold 0 (valid row)
            int s2 = __shfl(myidx, j + 2);
            int s3 = __shfl(myidx, j + 3);
            int s4 = __shfl(myidx, j + 4);
            int s5 = __shfl(myidx, j + 5);
            int s6 = __shfl(myidx, j + 6);
            int s7 = __shfl(myidx, j + 7);
            ushort2 u0 = xb2[(size_t)s0 * (D / 2) + lane];
            ushort2 u1 = xb2[(size_t)s1 * (D / 2) + lane];
            ushort2 u2 = xb2[(size_t)s2 * (D / 2) + lane];
            ushort2 u3 = xb2[(size_t)s3 * (D / 2) + lane];
            ushort2 u4 = xb2[(size_t)s4 * (D / 2) + lane];
            ushort2 u5 = xb2[(size_t)s5 * (D / 2) + lane];
            ushort2 u6 = xb2[(size_t)s6 * (D / 2) + lane];
            ushort2 u7 = xb2[(size_t)s7 * (D / 2) + lane];
            float m1 = (j + 1 < kk) ? 1.f : 0.f;
            float m2 = (j + 2 < kk) ? 1.f : 0.f;
            float m3 = (j + 3 < kk) ? 1.f : 0.f;
            float m4 = (j + 4 < kk) ? 1.f : 0.f;
            float m5 = (j + 5 < kk) ? 1.f : 0.f;
            float m6 = (j + 6 < kk) ? 1.f : 0.f;
            float m7 = (j + 7 < kk) ? 1.f : 0.f;
            ax += bf2f(u0.x) + m1 * bf2f(u1.x) + m2 * bf2f(u2.x) + m3 * bf2f(u3.x)
                + m4 * bf2f(u4.x) + m5 * bf2f(u5.x) + m6 * bf2f(u6.x) + m7 * bf2f(u7.x);
            ay += bf2f(u0.y) + m1 * bf2f(u1.y) + m2 * bf2f(u2.y) + m3 * bf2f(u3.y)
                + m4 * bf2f(u4.y) + m5 * bf2f(u5.y) + m6 * bf2f(u6.y) + m7 * bf2f(u7.y);
        }
        if (tov > 0) {                         // rare path; wave-uniform branch
            for (int t2 = 0; t2 < tov; ++t2) {
                if (ovf[2 * t2] == node) {
                    ushort2 u = xb2[(size_t)ovf[2 * t2 + 1] * (D / 2) + lane];
                    ax += bf2f(u.x);
                    ay += bf2f(u.y);
                }
            }
        }
        *(ushort2*)&sA[(wid * 4 + li) * SROW + 2 * lane] =
            make_ushort2(f2bf(ax), f2bf(ay));
    }
    __syncthreads();

    // ---- MFMA phase: wave wid computes n0 = 2*wid, 2*wid+1 ----
    int m = lane & 15, quad = lane >> 4;
    const unsigned short* arow = &sA[m * SROW + quad * 8];
    const unsigned short* xrow = xb + (size_t)(node0 + m) * D + quad * 8;

    floatx4 acc0 = (floatx4){0.f, 0.f, 0.f, 0.f};
    floatx4 acc1 = (floatx4){0.f, 0.f, 0.f, 0.f};
#pragma unroll
    for (int t = 0; t < 8; ++t) {
        short8 afrag = (t < 4) ? *(const short8*)(arow + t * 32)
                               : *(const short8*)(xrow + (t - 4) * 32);
        const unsigned short* bb = pwc + ((size_t)(t * 8 + wid * 2) * 64 + lane) * 8;
        short8 b0 = *(const short8*)bb;
        short8 b1 = *(const short8*)(bb + 64 * 8);
        acc0 = __builtin_amdgcn_mfma_f32_16x16x32_bf16(afrag, b0, acc0, 0, 0, 0);
        acc1 = __builtin_amdgcn_mfma_f32_16x16x32_bf16(afrag, b1, acc1, 0, 0, 0);
    }

#pragma unroll
    for (int q = 0; q < 2; ++q) {
        floatx4 a = q ? acc1 : acc0;
        int n = (wid * 2 + q) * 16 + m;
        float bias = b_rel[n];
#pragma unroll
        for (int r = 0; r < 4; ++r) {
            int node = node0 + quad * 4 + r;
            out[(size_t)node * D + n] = fmaxf(a[r] + bias, 0.f);
        }
    }
}

// ---------------- mid tier: fp32 CSR + VALU GEMM (unchanged machinery) ----------------
__global__ __launch_bounds__(256) void pack_w_kernel(const float* __restrict__ W,
                                                     float* __restrict__ pw) {
    int idx = blockIdx.x * 256 + threadIdx.x;
    if (idx >= D * D) return;
    int o = idx >> 7, k = idx & 127;
    pw[k * D + o] = W[o * D + k];
}

__global__ __launch_bounds__(256) void hist_kernel(const int* __restrict__ ei,
                                                   int* __restrict__ deg) {
    int i64 = wave_detect_i64(ei);
    int base = (blockIdx.x * 256 + threadIdx.x) * 4;
    if (base >= N_EDGES) return;
    int d0, d1, d2, d3;
    if (i64) {
        int4 a = *(const int4*)&ei[2 * N_EDGES + 2 * base];
        int4 b = *(const int4*)&ei[2 * N_EDGES + 2 * base + 4];
        d0 = a.x; d1 = a.z; d2 = b.x; d3 = b.z;
    } else {
        int4 v = *(const int4*)&ei[N_EDGES + base];
        d0 = v.x; d1 = v.y; d2 = v.z; d3 = v.w;
    }
    if ((unsigned)d0 < N_NODES) atomicAdd(&deg[d0], 1);
    if ((unsigned)d1 < N_NODES) atomicAdd(&deg[d1], 1);
    if ((unsigned)d2 < N_NODES) atomicAdd(&deg[d2], 1);
    if ((unsigned)d3 < N_NODES) atomicAdd(&deg[d3], 1);
}

__device__ __forceinline__ int wave_iscan(int v, int lane) {
#pragma unroll
    for (int off = 1; off < 64; off <<= 1) {
        int u = __shfl_up(v, off, 64);
        if (lane >= off) v += u;
    }
    return v;
}

__global__ __launch_bounds__(1024) void scan_kernel(const int* __restrict__ deg,
                                                    int* __restrict__ offsets,
                                                    int* __restrict__ cursor) {
    __shared__ int wsum[16];
    __shared__ int base_s;
    int t = threadIdx.x, lane = t & 63, w = t >> 6;
    if (t == 0) { base_s = 0; offsets[0] = 0; }
    __syncthreads();
    for (int c0 = 0; c0 < N_NODES; c0 += 1024) {
        int idx = c0 + t;
        int v = (idx < N_NODES) ? deg[idx] : 0;
        int inc = wave_iscan(v, lane);
        if (lane == 63) wsum[w] = inc;
        __syncthreads();
        if (w == 0) {
            int s = (lane < 16) ? wsum[lane] : 0;
            int si = wave_iscan(s, lane);
            if (lane < 16) wsum[lane] = si - s;
        }
        __syncthreads();
        int tot = base_s + wsum[w] + inc;
        if (idx < N_NODES) {
            offsets[idx + 1] = tot;
            cursor[idx] = tot - v;
        }
        __syncthreads();
        if (t == 1023) base_s = tot;
        __syncthreads();
    }
}

__global__ __launch_bounds__(256) void reorder_kernel(const int* __restrict__ ei,
                                                      int* __restrict__ cursor,
                                                      int* __restrict__ csr_src) {
    int i64 = wave_detect_i64(ei);
    int base = (blockIdx.x * 256 + threadIdx.x) * 4;
    if (base >= N_EDGES) return;
    int s0, s1, s2, s3, d0, d1, d2, d3;
    if (i64) {
        int4 a = *(const int4*)&ei[2 * base];
        int4 b = *(const int4*)&ei[2 * base + 4];
        s0 = a.x; s1 = a.z; s2 = b.x; s3 = b.z;
        int4 c = *(const int4*)&ei[2 * N_EDGES + 2 * base];
        int4 e = *(const int4*)&ei[2 * N_EDGES + 2 * base + 4];
        d0 = c.x; d1 = c.z; d2 = e.x; d3 = e.z;
    } else {
        int4 sv = *(const int4*)&ei[base];
        int4 dv = *(const int4*)&ei[N_EDGES + base];
        s0 = sv.x; s1 = sv.y; s2 = sv.z; s3 = sv.w;
        d0 = dv.x; d1 = dv.y; d2 = dv.z; d3 = dv.w;
    }
    bool v0 = (unsigned)s0 < N_NODES && (unsigned)d0 < N_NODES;
    bool v1 = (unsigned)s1 < N_NODES && (unsigned)d1 < N_NODES;
    bool v2 = (unsigned)s2 < N_NODES && (unsigned)d2 < N_NODES;
    bool v3 = (unsigned)s3 < N_NODES && (unsigned)d3 < N_NODES;
    int p0 = v0 ? atomicAdd(&cursor[d0], 1) : 0;
    int p1 = v1 ? atomicAdd(&cursor[d1], 1) : 0;
    int p2 = v2 ? atomicAdd(&cursor[d2], 1) : 0;
    int p3 = v3 ? atomicAdd(&cursor[d3], 1) : 0;
    if (v0) csr_src[p0] = s0;
    if (v1) csr_src[p1] = s1;
    if (v2) csr_src[p2] = s2;
    if (v3) csr_src[p3] = s3;
}

__global__ __launch_bounds__(256) void gather_kernel(const float2* __restrict__ x2,
                                                     const int* __restrict__ csr_src,
                                                     const int* __restrict__ offsets,
                                                     float2* __restrict__ agg2) {
    int node = blockIdx.x * 4 + (threadIdx.x >> 6);
    int lane = threadIdx.x & 63;
    if (node >= N_NODES) return;
    int beg = offsets[node], end = offsets[node + 1];
    float2 acc = make_float2(0.f, 0.f);
    for (int e = beg; e < end; ++e) {
        int s = csr_src[e];
        float2 f = x2[(size_t)s * (D / 2) + lane];
        acc.x += f.x;
        acc.y += f.y;
    }
    agg2[(size_t)node * (D / 2) + lane] = acc;
}

__global__ __launch_bounds__(256) void scatter_kernel(const float2* __restrict__ x2,
                                                      const int* __restrict__ ei,
                                                      const int* __restrict__ flag,
                                                      float* __restrict__ agg) {
    int wave = threadIdx.x >> 6;
    int lane = threadIdx.x & 63;
    int e = blockIdx.x * 4 + wave;
    if (e >= N_EDGES) return;
    int i64 = flag ? flag[0] : 0;
    int s, d;
    if (i64) { s = ei[2 * e]; d = ei[2 * N_EDGES + 2 * e]; }
    else     { s = ei[e];     d = ei[N_EDGES + e]; }
    if ((unsigned)s >= N_NODES || (unsigned)d >= N_NODES) return;
    float2 f = x2[(size_t)s * (D / 2) + lane];
    atomicAdd(&agg[(size_t)d * D + 2 * lane + 0], f.x);
    atomicAdd(&agg[(size_t)d * D + 2 * lane + 1], f.y);
}

__global__ __launch_bounds__(256) void gemm_f32_kernel(
        const float2* __restrict__ x2,
        const float* __restrict__ pwrel,
        const float* __restrict__ pwroot,
        const float* __restrict__ b_rel,
        float* __restrict__ out) {
    __shared__ float sWrel[KC * D];
    __shared__ float sWroot[KC * D];
    __shared__ float2 sAm[NPB * (KC / 2)];
    __shared__ float2 sXm[NPB * (KC / 2)];

    int t = threadIdx.x;
    int node0 = blockIdx.x * NPB;
    int tn = t >> 5;
    int to = t & 31;

    float acc[4][4];
#pragma unroll
    for (int a = 0; a < 4; ++a)
#pragma unroll
        for (int b = 0; b < 4; ++b) acc[a][b] = 0.0f;

    for (int c = 0; c < 4; ++c) {
        __syncthreads();
#pragma unroll
        for (int r = 0; r < 4; ++r) {
            int i = r * 256 + t;
            ((float4*)sWrel)[i]  = ((const float4*)(pwrel  + c * KC * D))[i];
            ((float4*)sWroot)[i] = ((const float4*)(pwroot + c * KC * D))[i];
        }
#pragma unroll
        for (int r = 0; r < 2; ++r) {
            int i = r * 256 + t;
            int n = i >> 4, k2 = i & 15;
            int node = node0 + n;
            float2 av = make_float2(0.f, 0.f), xv = make_float2(0.f, 0.f);
            if (node < N_NODES) {
                av = ((const float2*)out)[(size_t)node * (D / 2) + c * (KC / 2) + k2];
                xv = x2[(size_t)node * (D / 2) + c * (KC / 2) + k2];
            }
            sAm[i] = av;
            sXm[i] = xv;
        }
        __syncthreads();

#pragma unroll
        for (int k2 = 0; k2 < KC / 2; ++k2) {
            float4 wr0 = *(const float4*)&sWrel[(2 * k2 + 0) * D + to * 4];
            float4 wr1 = *(const float4*)&sWrel[(2 * k2 + 1) * D + to * 4];
            float4 wt0 = *(const float4*)&sWroot[(2 * k2 + 0) * D + to * 4];
            float4 wt1 = *(const float4*)&sWroot[(2 * k2 + 1) * D + to * 4];
#pragma unroll
            for (int ni = 0; ni < 4; ++ni) {
                float2 a  = sAm[(tn * 4 + ni) * (KC / 2) + k2];
                float2 xx = sXm[(tn * 4 + ni) * (KC / 2) + k2];
                acc[ni][0] += a.x * wr0.x + a.y * wr1.x + xx.x * wt0.x + xx.y * wt1.x;
                acc[ni][1] += a.x * wr0.y + a.y * wr1.y + xx.x * wt0.y + xx.y * wt1.y;
                acc[ni][2] += a.x * wr0.z + a.y * wr1.z + xx.x * wt0.z + xx.y * wt1.z;
                acc[ni][3] += a.x * wr0.w + a.y * wr1.w + xx.x * wt0.w + xx.y * wt1.w;
            }
        }
    }

    int o0 = to * 4;
    float4 bias = *(const float4*)&b_rel[o0];
#pragma unroll
    for (int ni = 0; ni < 4; ++ni) {
        int node = node0 + tn * 4 + ni;
        if (node >= N_NODES) continue;
        float4 v;
        v.x = fmaxf(acc[ni][0] + bias.x, 0.f);
        v.y = fmaxf(acc[ni][1] + bias.y, 0.f);
        v.z = fmaxf(acc[ni][2] + bias.z, 0.f);
        v.w = fmaxf(acc[ni][3] + bias.w, 0.f);
        *(float4*)&out[(size_t)node * D + o0] = v;
    }
}

__global__ __launch_bounds__(128) void gemm_fallback_kernel(const float* __restrict__ x,
                                                            const float* __restrict__ Wrel,
                                                            const float* __restrict__ Wroot,
                                                            const float* __restrict__ b_rel,
                                                            float* __restrict__ out) {
    __shared__ float rowA[D];
    __shared__ float rowX[D];
    int node = blockIdx.x;
    int o = threadIdx.x;
    rowA[o] = out[(size_t)node * D + o];
    rowX[o] = x[(size_t)node * D + o];
    __syncthreads();
    float acc = b_rel[o];
    const float4* wr = (const float4*)&Wrel[o * D];
    const float4* wt = (const float4*)&Wroot[o * D];
#pragma unroll 8
    for (int k4 = 0; k4 < D / 4; ++k4) {
        float4 w = wr[k4], u = wt[k4];
        const float* a = &rowA[k4 * 4];
        const float* xx = &rowX[k4 * 4];
        acc += a[0] * w.x + a[1] * w.y + a[2] * w.z + a[3] * w.w
             + xx[0] * u.x + xx[1] * u.y + xx[2] * u.z + xx[3] * u.w;
    }
    __syncthreads();
    out[(size_t)node * D + o] = fmaxf(acc, 0.f);
}

extern "C" void kernel_launch(void* const* d_in, const int* in_sizes, int n_in,
                              void* d_out, int out_size, void* d_ws, size_t ws_size,
                              hipStream_t stream) {
    const float* x      = (const float*)d_in[0];
    const int*   ei     = (const int*)d_in[1];
    const float* W_rel  = (const float*)d_in[2];
    const float* b_rel  = (const float*)d_in[3];
    const float* W_root = (const float*)d_in[4];
    float*       out    = (float*)d_out;

    // Full-tier ws layout (16 B aligned):
    //   flag(16) | pwc 64K | xb 12.8M | cnt 200K | ovf_cnt 16 | slots 9.6M |
    //   ovf 6.4M                                              total ~27.7 MiB
    char* p = (char*)d_ws;
    size_t o0 = 16;
    int*            flag    = (int*)p;
    unsigned short* pwc     = (unsigned short*)(p + o0);  o0 += (size_t)PACK_N * 2;
    unsigned short* xb      = (unsigned short*)(p + o0);  o0 += (size_t)N_NODES * D * 2;
    int*            cnt     = (int*)(p + o0);             o0 += (size_t)N_NODES * 4;
    int*            ovf_cnt = (int*)(p + o0);             o0 += 16;
    int*            slots   = (int*)(p + o0);             o0 += (size_t)N_NODES * SLOTS * 4;
    int*            ovf     = (int*)(p + o0);             o0 += (size_t)N_EDGES * 8;
    const size_t need_full = o0;

    // Mid-tier layout: flag | pwrel 64K | pwroot 64K | deg | offs | csr
    size_t m0 = 16;
    float* m_pwrel  = (float*)(p + m0);  m0 += (size_t)D * D * 4;
    float* m_pwroot = (float*)(p + m0);  m0 += (size_t)D * D * 4;
    int*   m_deg    = (int*)(p + m0);    m0 += (size_t)N_NODES * 4;
    int*   m_offs   = (int*)(p + m0);    m0 += ((size_t)N_NODES + 1) * 4 + 12;
    m0 &= ~15ull;
    int*   m_csr    = (int*)(p + m0);    m0 += (size_t)N_EDGES * 4;
    const size_t need_mid = m0;
    const size_t need_pw  = 16 + 2 * (size_t)D * D * 4;

    const int eb4 = (N_EDGES / 4 + 255) / 256;   // 782 blocks for 4-edge kernels

    if (ws_size >= need_full) {
        const int prep_total = CVT_N + PACK_N + N_NODES + 4;
        prep_kernel<<<(prep_total + 255) / 256, 256, 0, stream>>>(
            (const float2*)x, (ushort2*)xb, W_rel, W_root, pwc, cnt);
        append_kernel<<<eb4, 256, 0, stream>>>(ei, cnt, slots, ovf_cnt, ovf);
        GraphConvLayer_55783035240593_kernel<<<N_NODES / 16, 256, 0, stream>>>(
            (const ushort2*)xb, xb, cnt, slots, ovf_cnt, ovf, pwc, b_rel, out);
    } else if (ws_size >= need_mid) {
        pack_w_kernel<<<64, 256, 0, stream>>>(W_rel, m_pwrel);
        pack_w_kernel<<<64, 256, 0, stream>>>(W_root, m_pwroot);
        zero_f4_kernel<<<(N_NODES / 4 + 255) / 256, 256, 0, stream>>>((float4*)m_deg,
                                                                      N_NODES / 4);
        hist_kernel<<<eb4, 256, 0, stream>>>(ei, m_deg);
        scan_kernel<<<1, 1024, 0, stream>>>(m_deg, m_offs, m_deg);
        reorder_kernel<<<eb4, 256, 0, stream>>>(ei, m_deg, m_csr);
        gather_kernel<<<N_NODES / 4, 256, 0, stream>>>((const float2*)x, m_csr,
                                                       m_offs, (float2*)out);
        gemm_f32_kernel<<<(N_NODES + NPB - 1) / NPB, 256, 0, stream>>>(
            (const float2*)x, m_pwrel, m_pwroot, b_rel, out);
    } else {
        bool have_flag = ws_size >= 16;
        bool have_pw   = ws_size >= need_pw;
        if (have_flag) detect_kernel<<<1, 64, 0, stream>>>(ei, flag);
        if (have_pw) {
            pack_w_kernel<<<64, 256, 0, stream>>>(W_rel, m_pwrel);
            pack_w_kernel<<<64, 256, 0, stream>>>(W_root, m_pwroot);
        }
        int n4 = N_NODES * D / 4;
        zero_f4_kernel<<<(n4 + 255) / 256, 256, 0, stream>>>((float4*)out, n4);
        scatter_kernel<<<N_EDGES / 4, 256, 0, stream>>>((const float2*)x, ei,
                                                        have_flag ? flag : nullptr, out);
        if (have_pw)
            gemm_f32_kernel<<<(N_NODES + NPB - 1) / NPB, 256, 0, stream>>>(
                (const float2*)x, m_pwrel, m_pwroot, b_rel, out);
        else
            gemm_fallback_kernel<<<N_NODES, 128, 0, stream>>>(x, W_rel, W_root, b_rel, out);
    }
}